// Round 7
// baseline (250.710 us; speedup 1.0000x reference)
//
#include <hip/hip_runtime.h>
#include <stdint.h>

// SFFM — inputs [L=4,B=8,C=256,H=64,W=64] float32, W [256,256] float32.
//   gap    = mean(inputs, axis=(3,4))             -> [L,B,C]
//   scores = gap @ W^T                            -> [L,B,C]
//   attn   = softmax over L                       -> [L,B,C]
//   out    = inputs * attn[:,:,:,None,None]
//
// v7: A/B vs v6 — ONLY change: plain float4 stores instead of
// __builtin_nontemporal_store in the streamer. Evidence nt throttles:
// (a) harness fills hit 6.7 TB/s with plain writes; both nt variants
// (248.4/248.8) lose to the plain-store baseline (244.1) despite doing
// less per-block work; (b) R4's fused-kernel counters proved the input
// stays L3-resident even with 131 MB of concurrent output writes, so the
// nt hint's L3-protection role is unnecessary (input 128 MiB < 256 MiB LLC).
//   K1 GAP:   8192 blocks — unchanged
//   K2 attn:  2048 blocks — unchanged
//   K3 scale: persistent streamer (2048 blocks x 4 channels), plain stores
//
// Channel index: ch = (l*B + b)*C + d.

#define L_DIM 4
#define B_DIM 8
#define C_DIM 256
#define HW    4096                      // 64*64 per channel
#define F4_PER_CH (HW / 4)              // 1024 float4 per channel
#define NCH   (L_DIM * B_DIM * C_DIM)   // 8192 channels
#define NBD   (B_DIM * C_DIM)           // 2048 (b,d) pairs
#define SCALE_BLOCKS 2048               // 8 blocks/CU
#define CH_PER_BLOCK (NCH / SCALE_BLOCKS)   // 4

// ---- Kernel 1: GAP. One block (256 threads) per channel. ----
__global__ __launch_bounds__(256) void gap_kernel(
        const float4* __restrict__ in, float* __restrict__ gap) {
    const int ch = blockIdx.x;
    const float4* base = in + (size_t)ch * F4_PER_CH;
    float s = 0.0f;
    #pragma unroll
    for (int k = 0; k < 4; ++k) {
        float4 p = base[threadIdx.x + k * 256];
        s += (p.x + p.y) + (p.z + p.w);
    }
    #pragma unroll
    for (int off = 32; off > 0; off >>= 1)
        s += __shfl_down(s, off, 64);
    __shared__ float wsum[4];
    const int wave = threadIdx.x >> 6;
    const int lane = threadIdx.x & 63;
    if (lane == 0) wsum[wave] = s;
    __syncthreads();
    if (threadIdx.x == 0) {
        gap[ch] = (wsum[0] + wsum[1] + wsum[2] + wsum[3]) * (1.0f / (float)HW);
    }
}

// ---- Kernel 2: attention. One block per (b,d); writes attn for all 4 l. ----
__global__ __launch_bounds__(256) void attn_kernel(
        const float* __restrict__ gap, const float* __restrict__ Wf,
        float* __restrict__ attn) {
    const int bid = blockIdx.x;          // b*C + d
    const int d   = bid & (C_DIM - 1);
    const int b   = bid >> 8;
    const int c   = threadIdx.x;

    const float w = Wf[(size_t)d * C_DIM + c];          // coalesced row read
    float p0 = gap[(0 * B_DIM + b) * C_DIM + c] * w;
    float p1 = gap[(1 * B_DIM + b) * C_DIM + c] * w;
    float p2 = gap[(2 * B_DIM + b) * C_DIM + c] * w;
    float p3 = gap[(3 * B_DIM + b) * C_DIM + c] * w;

    #pragma unroll
    for (int off = 32; off > 0; off >>= 1) {
        p0 += __shfl_down(p0, off, 64);
        p1 += __shfl_down(p1, off, 64);
        p2 += __shfl_down(p2, off, 64);
        p3 += __shfl_down(p3, off, 64);
    }
    __shared__ float part[4][4];   // [wave][l']
    const int wave = threadIdx.x >> 6;
    const int lane = threadIdx.x & 63;
    if (lane == 0) {
        part[wave][0] = p0; part[wave][1] = p1;
        part[wave][2] = p2; part[wave][3] = p3;
    }
    __syncthreads();
    if (threadIdx.x < 4) {
        const float s0 = part[0][0] + part[1][0] + part[2][0] + part[3][0];
        const float s1 = part[0][1] + part[1][1] + part[2][1] + part[3][1];
        const float s2 = part[0][2] + part[1][2] + part[2][2] + part[3][2];
        const float s3 = part[0][3] + part[1][3] + part[2][3] + part[3][3];
        const float m  = fmaxf(fmaxf(s0, s1), fmaxf(s2, s3));
        const float e0 = __expf(s0 - m), e1 = __expf(s1 - m);
        const float e2 = __expf(s2 - m), e3 = __expf(s3 - m);
        const float inv = 1.0f / (e0 + e1 + e2 + e3);
        const int   l   = threadIdx.x;
        const float el  = (l == 0) ? e0 : (l == 1) ? e1 : (l == 2) ? e2 : e3;
        attn[(l * B_DIM + b) * C_DIM + d] = el * inv;
    }
}

// ---- Kernel 3: persistent streamer. 2048 blocks x 4 channels each. ----
// Channel-pair inner step: issue all 8 float4 loads, then scale+store 8.
// PLAIN stores this round (A/B vs v6's nt-stores).
__global__ __launch_bounds__(256) void scale_kernel(
        const float4* __restrict__ in, const float* __restrict__ attn,
        float4* __restrict__ out) {
    const int t   = threadIdx.x;
    const int ch0 = blockIdx.x * CH_PER_BLOCK;
    #pragma unroll
    for (int cc = 0; cc < CH_PER_BLOCK; cc += 2) {
        const int chA = ch0 + cc;
        const int chB = ch0 + cc + 1;
        const float aA = attn[chA];      // uniform -> scalar broadcast
        const float aB = attn[chB];
        const float4* sA = in + (size_t)chA * F4_PER_CH;
        const float4* sB = in + (size_t)chB * F4_PER_CH;
        float4 vA[4], vB[4];
        #pragma unroll
        for (int k = 0; k < 4; ++k) vA[k] = sA[t + k * 256];
        #pragma unroll
        for (int k = 0; k < 4; ++k) vB[k] = sB[t + k * 256];
        float4* dA = out + (size_t)chA * F4_PER_CH;
        float4* dB = out + (size_t)chB * F4_PER_CH;
        #pragma unroll
        for (int k = 0; k < 4; ++k) {
            float4 q;
            q.x = vA[k].x * aA; q.y = vA[k].y * aA;
            q.z = vA[k].z * aA; q.w = vA[k].w * aA;
            dA[t + k * 256] = q;
        }
        #pragma unroll
        for (int k = 0; k < 4; ++k) {
            float4 q;
            q.x = vB[k].x * aB; q.y = vB[k].y * aB;
            q.z = vB[k].z * aB; q.w = vB[k].w * aB;
            dB[t + k * 256] = q;
        }
    }
}

extern "C" void kernel_launch(void* const* d_in, const int* in_sizes, int n_in,
                              void* d_out, int out_size, void* d_ws, size_t ws_size,
                              hipStream_t stream) {
    const float4* in_p  = (const float4*)d_in[0];
    const float*  W_p   = (const float*)d_in[1];
    float4*       out_p = (float4*)d_out;

    float* gap  = (float*)d_ws;                  // 8192 floats
    float* attn = (float*)d_ws + NCH;            // 8192 floats

    gap_kernel  <<<NCH, 256, 0, stream>>>(in_p, gap);
    attn_kernel <<<NBD, 256, 0, stream>>>(gap, W_p, attn);
    scale_kernel<<<SCALE_BLOCKS, 256, 0, stream>>>(in_p, attn, out_p);
}

// Round 8
// 245.622 us; speedup vs baseline: 1.0207x; 1.0207x over previous
//
#include <hip/hip_runtime.h>
#include <stdint.h>

// SFFM — inputs [L=4,B=8,C=256,H=64,W=64] float32, W [256,256] float32.
//   gap    = mean(inputs, axis=(3,4))             -> [L,B,C]
//   scores = gap @ W^T                            -> [L,B,C]
//   attn   = softmax over L                       -> [L,B,C]
//   out    = inputs * attn[:,:,:,None,None]
//
// v8: 2-kernel structure, efficient merge. Ledger across R2-R7:
// dur_us = ~158 µs harness poison-fills (at BW ceiling, uncontrollable)
//        + ~86-92 µs kernels, for EVERY structure tried. Streamer levers
// (persistence, MLP, nt vs plain stores) all null -> mixed read+write
// streams run at the platform rate. The one counter-grounded delta left:
// the baseline's 2-dispatch structure beats our 3-dispatch by ~one launch
// boundary. So: merge attn into the streamer, but at 2048 blocks (one per
// (b,d)) — attention computed ONCE per (b,d) (baseline recomputed it 4x)
// and amortized over 64 KB of streaming instead of 16 KB.
//   K1 GAP:        8192 blocks, ~21 µs = 6.2 TB/s (at ceiling) — unchanged
//   K2 attn+scale: 2048 blocks; dot+softmax preamble, then stream 4
//                  channels (pairwise loads-then-stores, plain float4).
//
// Channel index: ch = (l*B + b)*C + d.

#define L_DIM 4
#define B_DIM 8
#define C_DIM 256
#define HW    4096                      // 64*64 per channel
#define F4_PER_CH (HW / 4)              // 1024 float4 per channel
#define NCH   (L_DIM * B_DIM * C_DIM)   // 8192 channels
#define NBD   (B_DIM * C_DIM)           // 2048 (b,d) pairs

// ---- Kernel 1: GAP. One block (256 threads) per channel. ----
__global__ __launch_bounds__(256) void gap_kernel(
        const float4* __restrict__ in, float* __restrict__ gap) {
    const int ch = blockIdx.x;
    const float4* base = in + (size_t)ch * F4_PER_CH;
    float s = 0.0f;
    #pragma unroll
    for (int k = 0; k < 4; ++k) {
        float4 p = base[threadIdx.x + k * 256];
        s += (p.x + p.y) + (p.z + p.w);
    }
    #pragma unroll
    for (int off = 32; off > 0; off >>= 1)
        s += __shfl_down(s, off, 64);
    __shared__ float wsum[4];
    const int wave = threadIdx.x >> 6;
    const int lane = threadIdx.x & 63;
    if (lane == 0) wsum[wave] = s;
    __syncthreads();
    if (threadIdx.x == 0) {
        gap[ch] = (wsum[0] + wsum[1] + wsum[2] + wsum[3]) * (1.0f / (float)HW);
    }
}

// ---- Kernel 2: attention + scale. One block per (b,d). ----
// Preamble: scores[l] = dot(gap[l,b,:], W[d,:]) via 256 threads + wave
// reduce; softmax over l in 4 threads. Then stream-scale the 4 channels
// (l=0..3) of this (b,d): 64 KB in / 64 KB out, pairwise load-then-store.
__global__ __launch_bounds__(256) void attn_scale_kernel(
        const float4* __restrict__ in, const float* __restrict__ gap,
        const float* __restrict__ Wf, float4* __restrict__ out) {
    const int bid = blockIdx.x;          // b*C + d
    const int d   = bid & (C_DIM - 1);
    const int b   = bid >> 8;
    const int t   = threadIdx.x;
    const int wave = t >> 6;
    const int lane = t & 63;

    const float w = Wf[(size_t)d * C_DIM + t];          // coalesced row read
    float p0 = gap[(0 * B_DIM + b) * C_DIM + t] * w;
    float p1 = gap[(1 * B_DIM + b) * C_DIM + t] * w;
    float p2 = gap[(2 * B_DIM + b) * C_DIM + t] * w;
    float p3 = gap[(3 * B_DIM + b) * C_DIM + t] * w;

    #pragma unroll
    for (int off = 32; off > 0; off >>= 1) {
        p0 += __shfl_down(p0, off, 64);
        p1 += __shfl_down(p1, off, 64);
        p2 += __shfl_down(p2, off, 64);
        p3 += __shfl_down(p3, off, 64);
    }
    __shared__ float part[4][4];   // [wave][l']
    __shared__ float a_s[4];
    if (lane == 0) {
        part[wave][0] = p0; part[wave][1] = p1;
        part[wave][2] = p2; part[wave][3] = p3;
    }
    __syncthreads();
    if (t < 4) {
        const float s0 = part[0][0] + part[1][0] + part[2][0] + part[3][0];
        const float s1 = part[0][1] + part[1][1] + part[2][1] + part[3][1];
        const float s2 = part[0][2] + part[1][2] + part[2][2] + part[3][2];
        const float s3 = part[0][3] + part[1][3] + part[2][3] + part[3][3];
        const float m  = fmaxf(fmaxf(s0, s1), fmaxf(s2, s3));
        const float e0 = __expf(s0 - m), e1 = __expf(s1 - m);
        const float e2 = __expf(s2 - m), e3 = __expf(s3 - m);
        const float inv = 1.0f / (e0 + e1 + e2 + e3);
        const float el  = (t == 0) ? e0 : (t == 1) ? e1 : (t == 2) ? e2 : e3;
        a_s[t] = el * inv;
    }
    __syncthreads();

    // stream the 4 channels of this (b,d), two at a time
    #pragma unroll
    for (int lp = 0; lp < L_DIM; lp += 2) {
        const float aA = a_s[lp];
        const float aB = a_s[lp + 1];
        const int chA = (((lp    ) * B_DIM + b) << 8) + d;
        const int chB = (((lp + 1) * B_DIM + b) << 8) + d;
        const float4* sA = in + (size_t)chA * F4_PER_CH;
        const float4* sB = in + (size_t)chB * F4_PER_CH;
        float4 vA[4], vB[4];
        #pragma unroll
        for (int k = 0; k < 4; ++k) vA[k] = sA[t + k * 256];
        #pragma unroll
        for (int k = 0; k < 4; ++k) vB[k] = sB[t + k * 256];
        float4* dA = out + (size_t)chA * F4_PER_CH;
        float4* dB = out + (size_t)chB * F4_PER_CH;
        #pragma unroll
        for (int k = 0; k < 4; ++k) {
            float4 q;
            q.x = vA[k].x * aA; q.y = vA[k].y * aA;
            q.z = vA[k].z * aA; q.w = vA[k].w * aA;
            dA[t + k * 256] = q;
        }
        #pragma unroll
        for (int k = 0; k < 4; ++k) {
            float4 q;
            q.x = vB[k].x * aB; q.y = vB[k].y * aB;
            q.z = vB[k].z * aB; q.w = vB[k].w * aB;
            dB[t + k * 256] = q;
        }
    }
}

extern "C" void kernel_launch(void* const* d_in, const int* in_sizes, int n_in,
                              void* d_out, int out_size, void* d_ws, size_t ws_size,
                              hipStream_t stream) {
    const float4* in_p  = (const float4*)d_in[0];
    const float*  W_p   = (const float*)d_in[1];
    float4*       out_p = (float4*)d_out;

    float* gap = (float*)d_ws;                   // 8192 floats

    gap_kernel      <<<NCH, 256, 0, stream>>>(in_p, gap);
    attn_scale_kernel<<<NBD, 256, 0, stream>>>(in_p, gap, W_p, out_p);
}